// Round 2
// baseline (1034.068 us; speedup 1.0000x reference)
//
#include <hip/hip_runtime.h>

#define DD 256
#define NN 512
#define BB 1024
#define MASK_NEG 1e30f

// ---------------------------------------------------------------------------
// Kernel 1: prep
//   M[e][d]  = sum_i W1[i][e] * W2[i][d]          (W1^T @ W2)
//   yb[d]    = sum_i b1[i]   * W2[i][d]           (b1 @ W2)
//   vw[d]    = sum_i W1[i][d] * b2[i]             (W1^T b2)
//   sc[0]    = b1 . b2
//   sc[1]    = rel_emb[0] . W3 + b3   (r0)
//   sc[2]    = rel_emb[1] . W3 + b3   (r1)
// ---------------------------------------------------------------------------
__global__ __launch_bounds__(256) void prep_kernel(
    const float* __restrict__ W1, const float* __restrict__ b1,
    const float* __restrict__ W2, const float* __restrict__ b2,
    const float* __restrict__ W3, const float* __restrict__ b3,
    const float* __restrict__ rel_emb,
    float* __restrict__ M, float* __restrict__ yb,
    float* __restrict__ vw, float* __restrict__ sc) {
  const int tid = threadIdx.x;
  if (blockIdx.x < DD) {
    const int e = blockIdx.x;
    float acc = 0.f;
    for (int i = 0; i < DD; ++i)
      acc += W1[i * DD + e] * W2[i * DD + tid];
    M[e * DD + tid] = acc;
  } else {
    float accyb = 0.f, accv = 0.f;
    for (int i = 0; i < DD; ++i) {
      accyb += b1[i] * W2[i * DD + tid];
      accv  += W1[i * DD + tid] * b2[i];
    }
    yb[tid] = accyb;
    vw[tid] = accv;
    if (tid == 0) {
      float s0 = 0.f;
      for (int i = 0; i < DD; ++i) s0 += b1[i] * b2[i];
      float r0 = b3[0], r1 = b3[0];
      for (int i = 0; i < DD; ++i) {
        r0 += rel_emb[i] * W3[i];
        r1 += rel_emb[DD + i] * W3[i];
      }
      sc[0] = s0; sc[1] = r0; sc[2] = r1;
    }
  }
}

// ---------------------------------------------------------------------------
// Kernel 2: qt[b][d] = yb[d] + sum_e Q[b][e] * M[e][d];  c[b] = sc0 + Q[b].vw
// ---------------------------------------------------------------------------
__global__ __launch_bounds__(256) void qt_kernel(
    const float* __restrict__ Q, const float* __restrict__ M,
    const float* __restrict__ yb, const float* __restrict__ vw,
    const float* __restrict__ sc,
    float* __restrict__ qt, float* __restrict__ cvec) {
  const int tid = threadIdx.x;
  const int b0 = blockIdx.x * 4;
  __shared__ float Qs[4][DD];
  __shared__ float red[256];

  for (int j = 0; j < 4; ++j)
    Qs[j][tid] = Q[(size_t)(b0 + j) * DD + tid];
  __syncthreads();

  float a0 = yb[tid];
  float a1 = a0, a2 = a0, a3 = a0;
  for (int e = 0; e < DD; ++e) {
    const float mm = M[e * DD + tid];
    a0 += Qs[0][e] * mm;
    a1 += Qs[1][e] * mm;
    a2 += Qs[2][e] * mm;
    a3 += Qs[3][e] * mm;
  }
  qt[(size_t)(b0 + 0) * DD + tid] = a0;
  qt[(size_t)(b0 + 1) * DD + tid] = a1;
  qt[(size_t)(b0 + 2) * DD + tid] = a2;
  qt[(size_t)(b0 + 3) * DD + tid] = a3;

  const float s0 = sc[0];
  const float vv = vw[tid];
  const int lane = tid & 63;
  for (int j = 0; j < 4; ++j) {
    red[tid] = Qs[j][tid] * vv;
    __syncthreads();
    if (tid < 128) red[tid] += red[tid + 128];
    __syncthreads();
    if (tid < 64) {
      float p = red[tid] + red[tid + 64];
      p += __shfl_xor(p, 32); p += __shfl_xor(p, 16); p += __shfl_xor(p, 8);
      p += __shfl_xor(p, 4);  p += __shfl_xor(p, 2);  p += __shfl_xor(p, 1);
      if (lane == 0) cvec[b0 + j] = s0 + p;
    }
    __syncthreads();
  }
}

// ---------------------------------------------------------------------------
// Kernel 3: per-b fused scores + softmax + weighted V sum. HBM-bound.
//   alpha[n] = K[b,n,:].qt[b,:] + c[b] + (s_mask? r1 : r0) - (1-adj)*1e30
//   w = softmax(alpha);  out_s[b,:] = sum_n w[n]*V[b,n,:]
// 1 block / b, 256 threads = 4 waves; wave w owns rows [w*128, w*128+128).
// Each row is one wave-wide float4 load (64 lanes x 16B = 1KB).
// Streaming loops unrolled x4 with loads batched ahead of the reduce chains
// to keep >=4 global_load_dwordx4 in flight per wave.
// ---------------------------------------------------------------------------
__global__ __launch_bounds__(256) void attn_kernel(
    const float* __restrict__ K, const float* __restrict__ V,
    const int* __restrict__ adj, const int* __restrict__ smask,
    const float* __restrict__ qt, const float* __restrict__ cvec,
    const float* __restrict__ sc,
    float* __restrict__ out_w, float* __restrict__ out_s) {
  const int b = blockIdx.x;
  const int tid = threadIdx.x;
  const int lane = tid & 63;
  const int w = tid >> 6;

  __shared__ float alpha[NN];
  __shared__ float bias[NN];
  __shared__ float4 accs[4][64];
  __shared__ float rred[2][4];

  const float r0 = sc[1], r1 = sc[2];
  const float cb = cvec[b];
  const size_t base = (size_t)b * NN * DD;
  const float4 qv = reinterpret_cast<const float4*>(qt + (size_t)b * DD)[lane];

  // per-row additive bias into LDS (coalesced int loads)
  for (int n = tid; n < NN; n += 256) {
    const float a = (float)adj[(size_t)b * NN + n];
    const float y = smask[(size_t)b * NN + n] ? r1 : r0;
    bias[n] = y + cb - (1.0f - a) * MASK_NEG;
  }
  __syncthreads();

  // phase 1: scores. 4 rows per iteration, loads batched first.
  const float4* Kb = reinterpret_cast<const float4*>(K + base);
  const int nbase = w << 7;
  for (int i = 0; i < 128; i += 4) {
    const int n = nbase + i;
    const float4 k0 = Kb[(size_t)(n + 0) * 64 + lane];
    const float4 k1 = Kb[(size_t)(n + 1) * 64 + lane];
    const float4 k2 = Kb[(size_t)(n + 2) * 64 + lane];
    const float4 k3 = Kb[(size_t)(n + 3) * 64 + lane];
    float p0 = k0.x * qv.x + k0.y * qv.y + k0.z * qv.z + k0.w * qv.w;
    float p1 = k1.x * qv.x + k1.y * qv.y + k1.z * qv.z + k1.w * qv.w;
    float p2 = k2.x * qv.x + k2.y * qv.y + k2.z * qv.z + k2.w * qv.w;
    float p3 = k3.x * qv.x + k3.y * qv.y + k3.z * qv.z + k3.w * qv.w;
#pragma unroll
    for (int s = 32; s >= 1; s >>= 1) {
      p0 += __shfl_xor(p0, s);
      p1 += __shfl_xor(p1, s);
      p2 += __shfl_xor(p2, s);
      p3 += __shfl_xor(p3, s);
    }
    if (lane == 0) {
      alpha[n + 0] = p0 + bias[n + 0];
      alpha[n + 1] = p1 + bias[n + 1];
      alpha[n + 2] = p2 + bias[n + 2];
      alpha[n + 3] = p3 + bias[n + 3];
    }
  }
  __syncthreads();

  // phase 2: softmax over 512 entries
  const float a0 = alpha[tid], a1 = alpha[tid + 256];
  float m = fmaxf(a0, a1);
  m = fmaxf(m, __shfl_xor(m, 32)); m = fmaxf(m, __shfl_xor(m, 16));
  m = fmaxf(m, __shfl_xor(m, 8));  m = fmaxf(m, __shfl_xor(m, 4));
  m = fmaxf(m, __shfl_xor(m, 2));  m = fmaxf(m, __shfl_xor(m, 1));
  if (lane == 0) rred[0][w] = m;
  __syncthreads();
  m = fmaxf(fmaxf(rred[0][0], rred[0][1]), fmaxf(rred[0][2], rred[0][3]));

  const float e0 = expf(a0 - m), e1 = expf(a1 - m);
  float s = e0 + e1;
  s += __shfl_xor(s, 32); s += __shfl_xor(s, 16); s += __shfl_xor(s, 8);
  s += __shfl_xor(s, 4);  s += __shfl_xor(s, 2);  s += __shfl_xor(s, 1);
  if (lane == 0) rred[1][w] = s;
  __syncthreads();
  s = rred[1][0] + rred[1][1] + rred[1][2] + rred[1][3];

  const float inv = 1.0f / s;
  const float w0 = e0 * inv, w1 = e1 * inv;
  out_w[(size_t)b * NN + tid] = w0;
  out_w[(size_t)b * NN + tid + 256] = w1;
  // all reads of alpha happened before the rred syncs above -> safe to reuse
  alpha[tid] = w0;
  alpha[tid + 256] = w1;
  __syncthreads();

  // phase 3: attn_sum = sum_n w[n] * V[b,n,:], unrolled x4
  const float4* Vb = reinterpret_cast<const float4*>(V + base);
  float4 acc = make_float4(0.f, 0.f, 0.f, 0.f);
  for (int i = 0; i < 128; i += 4) {
    const int n = nbase + i;
    const float4 v0 = Vb[(size_t)(n + 0) * 64 + lane];
    const float4 v1 = Vb[(size_t)(n + 1) * 64 + lane];
    const float4 v2 = Vb[(size_t)(n + 2) * 64 + lane];
    const float4 v3 = Vb[(size_t)(n + 3) * 64 + lane];
    const float t0 = alpha[n + 0], t1 = alpha[n + 1];
    const float t2 = alpha[n + 2], t3 = alpha[n + 3];
    acc.x += t0 * v0.x; acc.y += t0 * v0.y; acc.z += t0 * v0.z; acc.w += t0 * v0.w;
    acc.x += t1 * v1.x; acc.y += t1 * v1.y; acc.z += t1 * v1.z; acc.w += t1 * v1.w;
    acc.x += t2 * v2.x; acc.y += t2 * v2.y; acc.z += t2 * v2.z; acc.w += t2 * v2.w;
    acc.x += t3 * v3.x; acc.y += t3 * v3.y; acc.z += t3 * v3.z; acc.w += t3 * v3.w;
  }
  accs[w][lane] = acc;
  __syncthreads();
  if (w == 0) {
    const float4 t0 = accs[0][lane], t1 = accs[1][lane];
    const float4 t2 = accs[2][lane], t3 = accs[3][lane];
    float4 r;
    r.x = t0.x + t1.x + t2.x + t3.x;
    r.y = t0.y + t1.y + t2.y + t3.y;
    r.z = t0.z + t1.z + t2.z + t3.z;
    r.w = t0.w + t1.w + t2.w + t3.w;
    reinterpret_cast<float4*>(out_s + (size_t)b * DD)[lane] = r;
  }
}

// ---------------------------------------------------------------------------
extern "C" void kernel_launch(void* const* d_in, const int* in_sizes, int n_in,
                              void* d_out, int out_size, void* d_ws, size_t ws_size,
                              hipStream_t stream) {
  const float* Q     = (const float*)d_in[0];
  const float* K     = (const float*)d_in[1];
  const float* V     = (const float*)d_in[2];
  const int*   adj   = (const int*)d_in[3];
  const int*   smask = (const int*)d_in[4];
  const float* W1    = (const float*)d_in[5];
  const float* b1    = (const float*)d_in[6];
  const float* W2    = (const float*)d_in[7];
  const float* b2    = (const float*)d_in[8];
  const float* W3    = (const float*)d_in[9];
  const float* b3    = (const float*)d_in[10];
  const float* rel   = (const float*)d_in[11];

  float* out   = (float*)d_out;
  float* out_w = out;                       // (B,1,N) -> B*N floats
  float* out_s = out + (size_t)BB * NN;     // (B,D)   -> B*D floats

  float* wsf = (float*)d_ws;
  float* M   = wsf;                         // D*D      = 65536 floats
  float* yb  = M + DD * DD;                 // 256
  float* vw  = yb + DD;                     // 256
  float* sc  = vw + DD;                     // 3 (+1 pad)
  float* qtp = sc + 4;                      // B*D = 262144 (16B-aligned)
  float* cp  = qtp + (size_t)BB * DD;       // B = 1024

  prep_kernel<<<DD + 1, 256, 0, stream>>>(W1, b1, W2, b2, W3, b3, rel,
                                          M, yb, vw, sc);
  qt_kernel<<<BB / 4, 256, 0, stream>>>(Q, M, yb, vw, sc, qtp, cp);
  attn_kernel<<<BB, 256, 0, stream>>>(K, V, adj, smask, qtp, cp, sc,
                                      out_w, out_s);
}